// Round 8
// baseline (114.453 us; speedup 1.0000x reference)
//
#include <hip/hip_runtime.h>
#include <hip/hip_bf16.h>

// GNN2: 3-layer GAT over 16384 independent 32-node cliques.
// One WAVE per graph (4 graphs / 256-thread block), zero barriers.
// mfma_f32_16x16x32_bf16 for GEMMs + aggregation; scores fused into the GEMM
// via pre-multiplied Wa = W @ [a_src|a_dst] columns, pre-scaled by log2(e)
// (exp2-domain softmax, no max-subtraction). 8192 B LDS/wave (xb[32][128]
// XOR-swizzled, half-ht buffer, ss overlaid on dead xb rows) -> 5 blocks/CU.

typedef __attribute__((ext_vector_type(8))) short short8;
typedef __attribute__((ext_vector_type(4))) short short4v;
typedef __attribute__((ext_vector_type(4))) float f32x4;

#define MFMA16(a,b,c) __builtin_amdgcn_mfma_f32_16x16x32_bf16(a,b,c,0,0,0)
#define L2E 1.4426950408889634f
#define MEMBAR() asm volatile("" ::: "memory")

__device__ __forceinline__ short f2bf(float f) {
    __hip_bfloat16 h = __float2bfloat16(f);
    return *reinterpret_cast<short*>(&h);
}
__device__ __forceinline__ float fexp2(float x) { return __builtin_amdgcn_exp2f(x); }

// ---------------- pre-kernel: tiled transposed bf16 weights in ws ----------------
// Tile layout per layer: [nt][kc][16][32] bf16 — B-frag loads 1KB contiguous/wave.
//  wt1 [0,4608):       NT=9, KC=1. n=nt*16+c: n<128 -> W1[k][n] (k<16 else 0);
//                      n in 128..135 -> L2E * Wa1 col (n-128); else 0
//  wt2 [4608,23040):   NT=9, KC=4. same scheme for W2/Wa2
//  wt3 [23040,27136):  NT=2, KC=4. n<24 -> W3[k][n] (packed hd*6+dl);
//                      n in 24..31 -> L2E * Wa3 col (n-24)
__global__ __launch_bounds__(256) void build_wt(
    const float* __restrict__ W1, const float* __restrict__ as1, const float* __restrict__ ad1,
    const float* __restrict__ W2, const float* __restrict__ as2, const float* __restrict__ ad2,
    const float* __restrict__ W3, const float* __restrict__ as3, const float* __restrict__ ad3,
    short* __restrict__ ws)
{
    int i = blockIdx.x * 256 + threadIdx.x;
    float val = 0.f;
    if (i < 4608) {                       // layer 1 (KC=1 -> [n][k])
        int n = i >> 5, k = i & 31;
        if (k < 16) {
            if (n < 128) val = W1[k*128 + n];
            else if (n < 136) {
                int cc = n - 128; const float* a = (cc < 4) ? as1 : ad1;
                for (int dl = 0; dl < 32; ++dl)
                    val += W1[k*128 + (cc&3)*32 + dl] * a[(cc&3)*32 + dl];
                val *= L2E;
            }
        }
        ws[i] = f2bf(val);
    } else if (i < 23040) {               // layer 2
        int j = i - 4608;
        int kq = j & 31, c = (j >> 5) & 15, kc = (j >> 9) & 3, nt = j >> 11;
        int n = nt*16 + c, k = kc*32 + kq;
        if (n < 128) val = W2[k*128 + n];
        else if (n < 136) {
            int cc = n - 128; const float* a = (cc < 4) ? as2 : ad2;
            for (int dl = 0; dl < 32; ++dl)
                val += W2[k*128 + (cc&3)*32 + dl] * a[(cc&3)*32 + dl];
            val *= L2E;
        }
        ws[i] = f2bf(val);
    } else {                              // layer 3 (packed 24 + 8 score)
        int j = i - 23040;
        int kq = j & 31, c = (j >> 5) & 15, kc = (j >> 9) & 3, nt = j >> 11;
        int n = nt*16 + c, k = kc*32 + kq;
        if (n < 24) val = W3[k*24 + n];
        else {
            int cc = n - 24; const float* a = (cc < 4) ? as3 : ad3;
            for (int dl = 0; dl < 6; ++dl)
                val += W3[k*24 + (cc&3)*6 + dl] * a[(cc&3)*6 + dl];
            val *= L2E;
        }
        ws[i] = f2bf(val);
    }
}

// ---------------- main-kernel phases ----------------
// Fragment layout (gfx950 16x16x32 bf16): A: row=lane&15, k=8*(lane>>4)+v;
// B: col=lane&15, k=8*(lane>>4)+v; D: col=lane&15, row=4*(lane>>4)+r. [m89/m93]
// xb: [32][128] bf16, 8-short granule g of row i stored at g ^ (i & MSK).
// ht: half-buffer [64][32] bf16, 4-short granule gl of row rl at gl ^ ((rl&15)>>1).
// ss: f32[8][32] overlaid at shorts [2048,2560) (xb rows 16..19, dead then).

template<int KC>
__device__ __forceinline__ void preload_a(const short* xb, int c, int q, short8 (&afr)[2][KC])
{
    constexpr int MSK = (KC == 1) ? 3 : 7;
    #pragma unroll
    for (int mt = 0; mt < 2; ++mt)
      #pragma unroll
      for (int kc = 0; kc < KC; ++kc)
        afr[mt][kc] = *(const short8*)&xb[(mt*16 + c)*128 + ((kc*4 + q) ^ (c & MSK))*8];
}

template<int KC>
__device__ __forceinline__ void score_col(const short8 (&afr)[2][KC], const short* __restrict__ wt,
                                          float* ss, int c, int q)
{
    const f32x4 zf = {0.f, 0.f, 0.f, 0.f};
    f32x4 a0 = zf, a1 = zf;
    #pragma unroll
    for (int kc = 0; kc < KC; ++kc) {
        short8 bfr = *(const short8*)&wt[((8*KC + kc)*16 + c)*32 + q*8];
        a0 = MFMA16(afr[0][kc], bfr, a0);
        a1 = MFMA16(afr[1][kc], bfr, a1);
    }
    if (c < 8) {          // rows c<4 = s_src head c, c>=4 = s_dst head c-4
        *(f32x4*)&ss[c*32 + q*4]      = a0;
        *(f32x4*)&ss[c*32 + 16 + q*4] = a1;
    }
}

template<int KC>
__device__ __forceinline__ void gemm_half(const short8 (&afr)[2][KC], const short* __restrict__ wt,
                                          short* ht, int h, int c, int q)
{
    const f32x4 zf = {0.f, 0.f, 0.f, 0.f};
    int sw = c >> 1;
    #pragma unroll
    for (int ntl = 0; ntl < 4; ++ntl) {
        int nt = h*4 + ntl;
        f32x4 a0 = zf, a1 = zf;
        #pragma unroll
        for (int kc = 0; kc < KC; ++kc) {
            short8 bfr = *(const short8*)&wt[((nt*KC + kc)*16 + c)*32 + q*8];
            a0 = MFMA16(afr[0][kc], bfr, a0);
            a1 = MFMA16(afr[1][kc], bfr, a1);
        }
        short4v h0, h1;
        #pragma unroll
        for (int r = 0; r < 4; ++r) { h0[r] = f2bf(a0[r]); h1[r] = f2bf(a1[r]); }
        int rl = ntl*16 + c;
        *(short4v*)&ht[rl*32 + ((q ^ sw))*4]     = h0;
        *(short4v*)&ht[rl*32 + (((4+q) ^ sw))*4] = h1;
    }
}

__device__ __forceinline__ void agg_half(const short* ht, const float* ss, int h,
                                         int c, int q, f32x4 (&acc)[4][2], float (&rdh)[2][2])
{
    const f32x4 zf = {0.f, 0.f, 0.f, 0.f};
    int sw = c >> 1;
    #pragma unroll
    for (int hh = 0; hh < 2; ++hh) {
        int hd = h*2 + hh;
        f32x4 v0 = *(const f32x4*)&ss[hd*32 + q*8];
        f32x4 v1 = *(const f32x4*)&ss[hd*32 + q*8 + 4];
        short8 pf[2];
        #pragma unroll
        for (int it = 0; it < 2; ++it) {
            float sd = ss[(4+hd)*32 + it*16 + c];
            float den = 0.f; short8 t;
            #pragma unroll
            for (int v = 0; v < 8; ++v) {
                float sj = (v < 4) ? v0[v] : v1[v-4];
                float e = sd + sj; e = fmaxf(e, 0.2f*e);   // lrelu, log2 domain
                float p = fexp2(e);
                den += p;
                t[v] = f2bf(p);
            }
            den += __shfl_xor(den, 16, 64);
            den += __shfl_xor(den, 32, 64);
            pf[it] = t; rdh[hh][it] = 1.0f / den;
        }
        #pragma unroll
        for (int m2 = 0; m2 < 2; ++m2) {
            int mtl = hh*2 + m2, rl = mtl*16 + c;
            short4v lo = *(const short4v*)&ht[rl*32 + ((2*q)   ^ sw)*4];
            short4v hi = *(const short4v*)&ht[rl*32 + ((2*q+1) ^ sw)*4];
            short8 af = __builtin_shufflevector(lo, hi, 0,1,2,3,4,5,6,7);
            acc[mtl][0] = MFMA16(af, pf[0], zf);
            acc[mtl][1] = MFMA16(af, pf[1], zf);
        }
    }
}

__device__ __forceinline__ void finish_half(const f32x4 (&acc)[4][2], const float (&rdh)[2][2],
                                            const float* bias, int h, int q, short4v (&pend)[4][2])
{
    #pragma unroll
    for (int mtl = 0; mtl < 4; ++mtl) {
        int mt = h*4 + mtl;
        f32x4 bv = *(const f32x4*)&bias[mt*16 + q*4];
        #pragma unroll
        for (int nt = 0; nt < 2; ++nt) {
            float rd = rdh[mtl >> 1][nt];
            short4v o;
            #pragma unroll
            for (int r = 0; r < 4; ++r) o[r] = f2bf(fmaf(acc[mtl][nt][r], rd, bv[r]));
            pend[mtl][nt] = o;
        }
    }
}

__device__ __forceinline__ void write_xb(const short4v (&p0)[4][2], const short4v (&p1)[4][2],
                                         short* xb, int c, int q)
{
    #pragma unroll
    for (int h = 0; h < 2; ++h)
      #pragma unroll
      for (int mtl = 0; mtl < 4; ++mtl) {
        int mt = h*4 + mtl;
        #pragma unroll
        for (int nt = 0; nt < 2; ++nt) {
            int ii = nt*16 + c;
            short4v val = h ? p1[mtl][nt] : p0[mtl][nt];
            *(short4v*)&xb[ii*128 + ((2*mt + (q>>1)) ^ (ii & 7))*8 + (q & 1)*4] = val;
        }
      }
}

template<int KC>
__device__ __forceinline__ void layer12(short* buf, const short* __restrict__ wt,
                                        const float* bias, int c, int q)
{
    float* ss = reinterpret_cast<float*>(buf + 2048);
    short8 afr[2][KC];
    preload_a<KC>(buf, c, q, afr);
    MEMBAR();
    score_col<KC>(afr, wt, ss, c, q);
    f32x4 acc[4][2]; float rdh[2][2];
    short4v pend0[4][2], pend1[4][2];
    gemm_half<KC>(afr, wt, buf, 0, c, q);
    agg_half(buf, ss, 0, c, q, acc, rdh);
    finish_half(acc, rdh, bias, 0, q, pend0);
    gemm_half<KC>(afr, wt, buf, 1, c, q);
    agg_half(buf, ss, 1, c, q, acc, rdh);
    finish_half(acc, rdh, bias, 1, q, pend1);
    MEMBAR();
    write_xb(pend0, pend1, buf, c, q);
    MEMBAR();
}

// Layer 3: packed 24+8 GEMM (NT=2), head-padded ht rows (64 rows), P-as-A agg,
// in-register node-mean -> mcol[24] (overlaid on ss).
__device__ __forceinline__ void layer3(short* buf, const short* __restrict__ wt,
                                       const float* b3, int c, int q, int lane)
{
    const f32x4 zf = {0.f, 0.f, 0.f, 0.f};
    float* ss = reinterpret_cast<float*>(buf + 2048);
    short8 afr[2][4];
    preload_a<4>(buf, c, q, afr);
    MEMBAR();
    {   // zero-fill pad rows hd*16+dl, dl in 6..15 (40 rows x 8 granules)
        const short4v z4 = {0, 0, 0, 0};
        #pragma unroll
        for (int k = 0; k < 5; ++k) {
            int flat = lane + k*64;
            int z = flat >> 3, gg = flat & 7;
            int row = (z/10)*16 + 6 + (z%10);
            *(short4v*)&buf[row*32 + gg*4] = z4;
        }
    }
    #pragma unroll
    for (int nt = 0; nt < 2; ++nt) {
        f32x4 a0 = zf, a1 = zf;
        #pragma unroll
        for (int kc = 0; kc < 4; ++kc) {
            short8 bfr = *(const short8*)&wt[((nt*4 + kc)*16 + c)*32 + q*8];
            a0 = MFMA16(afr[0][kc], bfr, a0);
            a1 = MFMA16(afr[1][kc], bfr, a1);
        }
        int p = nt*16 + c;
        if (p < 24) {
            int row = (p/6)*16 + (p%6);
            int sw3 = (row & 15) >> 1;
            short4v h0, h1;
            #pragma unroll
            for (int r = 0; r < 4; ++r) { h0[r] = f2bf(a0[r]); h1[r] = f2bf(a1[r]); }
            *(short4v*)&buf[row*32 + ((q ^ sw3))*4]     = h0;
            *(short4v*)&buf[row*32 + (((4+q) ^ sw3))*4] = h1;
        } else if (c >= 8) {   // score cols
            *(f32x4*)&ss[(c-8)*32 + q*4]      = a0;
            *(f32x4*)&ss[(c-8)*32 + 16 + q*4] = a1;
        }
    }
    MEMBAR();
    int sw = c >> 1;
    float vout[4];
    #pragma unroll
    for (int hd = 0; hd < 4; ++hd) {
        f32x4 v0 = *(const f32x4*)&ss[hd*32 + q*8];
        f32x4 v1 = *(const f32x4*)&ss[hd*32 + q*8 + 4];
        short8 pf[2];
        #pragma unroll
        for (int it = 0; it < 2; ++it) {
            float sd = ss[(4+hd)*32 + it*16 + c];
            float pv[8]; float den = 0.f;
            #pragma unroll
            for (int v = 0; v < 8; ++v) {
                float sj = (v < 4) ? v0[v] : v1[v-4];
                float e = sd + sj; e = fmaxf(e, 0.2f*e);
                pv[v] = fexp2(e);
                den += pv[v];
            }
            den += __shfl_xor(den, 16, 64);
            den += __shfl_xor(den, 32, 64);
            float rd = 1.0f / den;
            short8 t;
            #pragma unroll
            for (int v = 0; v < 8; ++v) t[v] = f2bf(pv[v] * rd);
            pf[it] = t;
        }
        int rl = hd*16 + c;
        short4v lo = *(const short4v*)&buf[rl*32 + ((2*q)   ^ sw)*4];
        short4v hi = *(const short4v*)&buf[rl*32 + ((2*q+1) ^ sw)*4];
        short8 bf_ = __builtin_shufflevector(lo, hi, 0,1,2,3,4,5,6,7);
        f32x4 o0 = MFMA16(pf[0], bf_, zf);   // D: row=i(4q+r), col=dl(c) in head hd
        f32x4 o1 = MFMA16(pf[1], bf_, zf);
        float s = (o0[0]+o0[1]) + (o0[2]+o0[3]) + (o1[0]+o1[1]) + (o1[2]+o1[3]);
        s += __shfl_xor(s, 16, 64);
        s += __shfl_xor(s, 32, 64);
        vout[hd] = s;
    }
    MEMBAR();
    if (q == 0 && c < 6) {
        #pragma unroll
        for (int hd = 0; hd < 4; ++hd)
            ss[hd*6 + c] = vout[hd] * (1.f/32.f) + b3[hd*6 + c];
    }
    MEMBAR();
}

__global__ __launch_bounds__(256, 5) void gat_mfma(
    const float* __restrict__ xs, const float* __restrict__ pe,
    const short* __restrict__ ws,
    const float* __restrict__ b1, const float* __restrict__ b2, const float* __restrict__ b3,
    const float* __restrict__ LW, const float* __restrict__ lb,
    float* __restrict__ out, int R)
{
    __shared__ short buf[4][4096];   // 8192 B/wave: xb[32][128] <-> ht[64][32]+ss

    int t = threadIdx.x;
    int w = t >> 6, lane = t & 63;
    int c = lane & 15, q = lane >> 4;
    int g = blockIdx.x * 4 + w;
    int b = g / R;

    short* xb = buf[w];

    // ---- build x0 [32][32] bf16 (cols 16..31 zero, granule-swizzled mask 3) ----
    {
        int j = lane >> 1, half = lane & 1;
        float v[8];
        if (half == 0) {
            v[0] = xs[g*32 + j];
            #pragma unroll
            for (int kk = 0; kk < 7; ++kk) v[1+kk] = pe[b*480 + j*15 + kk];
        } else {
            #pragma unroll
            for (int kk = 0; kk < 8; ++kk) v[kk] = pe[b*480 + j*15 + 7 + kk];
        }
        short8 px;
        #pragma unroll
        for (int kk = 0; kk < 8; ++kk) px[kk] = f2bf(v[kk]);
        int s3 = j & 3;
        *(short8*)&xb[j*128 + (half ^ s3)*8]       = px;
        *(short8*)&xb[j*128 + (((2+half) ^ s3))*8] = (short8){0,0,0,0,0,0,0,0};
    }
    MEMBAR();

    const short* wt1 = ws;
    const short* wt2 = ws + 4608;
    const short* wt3 = ws + 23040;

    layer12<1>(xb, wt1, b1, c, q);
    layer12<4>(xb, wt2, b2, c, q);
    layer3(xb, wt3, b3, c, q, lane);

    // ---- epilogue: out[g] = mcol @ lin_w + lin_b (f32) ----
    {
        const float* ss = reinterpret_cast<const float*>(xb + 2048);
        float o = lb[lane];
        #pragma unroll
        for (int cc = 0; cc < 24; ++cc)
            o = fmaf(ss[cc], LW[cc*64 + lane], o);
        out[g*64 + lane] = o;
    }
}

extern "C" void kernel_launch(void* const* d_in, const int* in_sizes, int n_in,
                              void* d_out, int out_size, void* d_ws, size_t ws_size,
                              hipStream_t stream) {
    const float* xs  = (const float*)d_in[0];
    const float* pe  = (const float*)d_in[1];
    const float* W1  = (const float*)d_in[2];
    const float* as1 = (const float*)d_in[3];
    const float* ad1 = (const float*)d_in[4];
    const float* b1  = (const float*)d_in[5];
    const float* W2  = (const float*)d_in[6];
    const float* as2 = (const float*)d_in[7];
    const float* ad2 = (const float*)d_in[8];
    const float* b2  = (const float*)d_in[9];
    const float* W3  = (const float*)d_in[10];
    const float* as3 = (const float*)d_in[11];
    const float* ad3 = (const float*)d_in[12];
    const float* b3  = (const float*)d_in[13];
    const float* LW  = (const float*)d_in[14];
    const float* lb  = (const float*)d_in[15];
    float* o = (float*)d_out;
    short* ws = (short*)d_ws;

    int G = in_sizes[0] / 32;       // B*R graphs (16384)
    int B = in_sizes[1] / 480;      // pos_enc = B*32*15
    int R = G / B;

    build_wt<<<dim3(106), dim3(256), 0, stream>>>(W1, as1, ad1, W2, as2, ad2,
                                                  W3, as3, ad3, ws);
    gat_mfma<<<dim3(G/4), dim3(256), 0, stream>>>(xs, pe, ws, b1, b2, b3, LW, lb, o, R);
}